// Round 4
// baseline (419.159 us; speedup 1.0000x reference)
//
#include <hip/hip_runtime.h>
#include <stdint.h>

#define B_ROWS  131072
#define D_DIM   512
#define BM      64
#define THREADS 512                         // 8 waves
#define NBLOCKS 256                         // 1 block/CU, persistent
#define NTILES  (B_ROWS / BM)               // 2048
#define TPB     (NTILES / NBLOCKS)          // 8 tiles per block

typedef __attribute__((ext_vector_type(8))) __bf16 bf16x8;
typedef __attribute__((ext_vector_type(4))) float  f32x4;

__device__ __forceinline__ unsigned short f32_to_bf16_rne(float f) {
    uint32_t u = __builtin_bit_cast(uint32_t, f);
    u += 0x7FFFu + ((u >> 16) & 1u);
    return (unsigned short)(u >> 16);
}

// Repack L (fp32 row-major [K=512][N=512]) into bf16 fragment order:
// flat ushort idx = ((ks*32 + ntg)*64 + lane)*8 + e  holds L[k][n],
//   n = ntg*16 + (lane&15),  k = ks*32 + (lane>>4)*8 + e.
__global__ void prep_lt(const float* __restrict__ L, unsigned short* __restrict__ Ltf) {
    int o = blockIdx.x * 256 + threadIdx.x;
    #pragma unroll
    for (int i = 0; i < 4; ++i) {
        int idx  = o + i * 65536;
        int e    = idx & 7;
        int l    = (idx >> 3) & 63;
        int tile = idx >> 9;
        int ntg  = tile & 31;
        int ks   = tile >> 5;
        int n    = ntg * 16 + (l & 15);
        int k    = ks * 32 + (l >> 4) * 8 + e;
        Ltf[idx] = f32_to_bf16_rne(L[k * 512 + n]);
    }
}

// b-tap fragment: a B-operand tile whose column 0 is b (cols 1..15 zero).
// MFMA with it puts x_row . b into C col 0 (lanes ln==0), same C/D layout
// as the main accumulators.
__global__ void prep_bt(const float* __restrict__ b, unsigned short* __restrict__ Btf) {
    int idx = blockIdx.x * 256 + threadIdx.x;   // 8192 items
    int e  = idx & 7;
    int l  = (idx >> 3) & 63;
    int ks = idx >> 9;
    int ln = l & 15, g = l >> 4;
    float v = (ln == 0) ? b[ks * 32 + g * 8 + e] : 0.f;
    Btf[idx] = f32_to_bf16_rne(v);
}

__global__ __launch_bounds__(THREADS, 2)
void psd_main(const float* __restrict__ x, const unsigned short* __restrict__ Ltf,
              const unsigned short* __restrict__ Btf,
              const float* __restrict__ c, float* __restrict__ out) {
    __shared__ __align__(16) unsigned short As[2][BM * D_DIM];  // 128 KiB, XOR-swizzled
    __shared__ float wpart[8][BM];

    const int t    = threadIdx.x;
    const int w    = t >> 6;          // wave 0..7 owns n-cols [w*64, w*64+64)
    const int lane = t & 63;
    const int g    = lane >> 4;
    const int ln   = lane & 15;
    const int swz  = (ln & 7) << 4;

    const unsigned short* LtW = Ltf + (size_t)w * 2048 + lane * 8;
    const unsigned short* BtL = Btf + lane * 8;

    // ---- prologue: stage tile 0 into As[0] ----
    {
        const float4* xg = (const float4*)(x + (size_t)blockIdx.x * BM * D_DIM);
        float4 v[16];
        #pragma unroll
        for (int i = 0; i < 16; ++i) v[i] = xg[i * THREADS + t];
        char* dst = (char*)As[0];
        #pragma unroll
        for (int i = 0; i < 16; ++i) {
            int f = i * THREADS + t, row = f >> 7, col4 = f & 127;
            ushort4 h;
            h.x = f32_to_bf16_rne(v[i].x); h.y = f32_to_bf16_rne(v[i].y);
            h.z = f32_to_bf16_rne(v[i].z); h.w = f32_to_bf16_rne(v[i].w);
            *(ushort4*)(dst + row * 1024 + ((col4 * 8) ^ ((row & 7) << 4))) = h;
        }
    }
    __syncthreads();

    #pragma unroll 1
    for (int tt = 0; tt < TPB; ++tt) {
        const int tile = blockIdx.x + NBLOCKS * tt;
        char* AsB = (char*)As[tt & 1];
        const bool has_next = (tt + 1 < TPB);

        // ---- issue next tile's global loads; they fly during the K-loop ----
        float4 v[16];
        if (has_next) {
            const float4* xg = (const float4*)(x + (size_t)(tile + NBLOCKS) * BM * D_DIM);
            #pragma unroll
            for (int i = 0; i < 16; ++i) v[i] = xg[i * THREADS + t];
        }

        // ---- K-loop: A from LDS, B double-buffered from L2 ----
        f32x4 acc[4][4];
        f32x4 accb[4];
        #pragma unroll
        for (int m = 0; m < 4; ++m) {
            accb[m] = (f32x4){0.f, 0.f, 0.f, 0.f};
            #pragma unroll
            for (int n = 0; n < 4; ++n) acc[m][n] = (f32x4){0.f, 0.f, 0.f, 0.f};
        }

        bf16x8 bcur[4], bnxt[4];
        #pragma unroll
        for (int nt = 0; nt < 4; ++nt) bcur[nt] = *(const bf16x8*)(LtW + nt * 512);

        #pragma unroll
        for (int ks = 0; ks < 16; ++ks) {
            const int ks1 = (ks + 1) & 15;
            #pragma unroll
            for (int nt = 0; nt < 4; ++nt)
                bnxt[nt] = *(const bf16x8*)(LtW + ks1 * 16384 + nt * 512);

            bf16x8 a[4];
            int cb = ((ks * 64 + g * 16) ^ swz);
            #pragma unroll
            for (int m = 0; m < 4; ++m)
                a[m] = *(const bf16x8*)(AsB + (m * 16 + ln) * 1024 + cb);

            if (w == 0) {
                bf16x8 bb = *(const bf16x8*)(BtL + ks * 512);
                #pragma unroll
                for (int m = 0; m < 4; ++m)
                    accb[m] = __builtin_amdgcn_mfma_f32_16x16x32_bf16(a[m], bb, accb[m], 0, 0, 0);
            }
            #pragma unroll
            for (int nt = 0; nt < 4; ++nt)
                #pragma unroll
                for (int m = 0; m < 4; ++m)
                    acc[m][nt] = __builtin_amdgcn_mfma_f32_16x16x32_bf16(a[m], bcur[nt], acc[m][nt], 0, 0, 0);
            #pragma unroll
            for (int nt = 0; nt < 4; ++nt) bcur[nt] = bnxt[nt];
        }

        // ---- rowsum of squares; C/D: col=lane&15, row=4*(lane>>4)+reg ----
        #pragma unroll
        for (int m = 0; m < 4; ++m) {
            #pragma unroll
            for (int r = 0; r < 4; ++r) {
                float s = 0.f;
                #pragma unroll
                for (int nt = 0; nt < 4; ++nt) { float vv = acc[m][nt][r]; s += vv * vv; }
                s += __shfl_xor(s, 1);
                s += __shfl_xor(s, 2);
                s += __shfl_xor(s, 4);
                s += __shfl_xor(s, 8);
                if (ln == 0) {
                    if (w == 0) s += accb[m][r];      // x.b tap (col 0)
                    wpart[w][m * 16 + g * 4 + r] = s;
                }
            }
        }
        __syncthreads();   // #1: wpart ready; all waves done reading As[tt&1]

        // ---- combine + store (wave 0) || stage next tile into As[(tt+1)&1] ----
        if (t < BM) {
            float y = c[0];
            #pragma unroll
            for (int k = 0; k < 8; ++k) y += wpart[k][t];
            out[(size_t)tile * BM + t] = y;
        }
        if (has_next) {
            char* dst = (char*)As[(tt + 1) & 1];
            #pragma unroll
            for (int i = 0; i < 16; ++i) {
                int f = i * THREADS + t, row = f >> 7, col4 = f & 127;
                ushort4 h;
                h.x = f32_to_bf16_rne(v[i].x); h.y = f32_to_bf16_rne(v[i].y);
                h.z = f32_to_bf16_rne(v[i].z); h.w = f32_to_bf16_rne(v[i].w);
                *(ushort4*)(dst + row * 1024 + ((col4 * 8) ^ ((row & 7) << 4))) = h;
            }
        }
        __syncthreads();   // #2: next buffer staged
    }
}

extern "C" void kernel_launch(void* const* d_in, const int* in_sizes, int n_in,
                              void* d_out, int out_size, void* d_ws, size_t ws_size,
                              hipStream_t stream) {
    const float* x = (const float*)d_in[0];
    const float* L = (const float*)d_in[1];
    const float* b = (const float*)d_in[2];
    const float* c = (const float*)d_in[3];
    float* out = (float*)d_out;
    unsigned short* Ltf = (unsigned short*)d_ws;     // 512 KiB
    unsigned short* Btf = Ltf + 262144;              // +16 KiB

    prep_lt<<<256, 256, 0, stream>>>(L, Ltf);
    prep_bt<<<32, 256, 0, stream>>>(b, Btf);
    psd_main<<<NBLOCKS, THREADS, 0, stream>>>(x, Ltf, Btf, c, out);
}

// Round 5
// 143.290 us; speedup vs baseline: 2.9253x; 2.9253x over previous
//
#include <hip/hip_runtime.h>
#include <stdint.h>

#define D_DIM   512
#define BM      128
#define THREADS 512            // 8 waves
#define NBLOCKS 256            // persistent, 1 block/CU (VGPR-forced)
#define ROWS_PER_BLOCK 512     // 4 tiles of 128 rows
#define NSTEPS  16             // 4 tiles x 4 K-quarters

typedef __attribute__((ext_vector_type(8))) __bf16 bf16x8;
typedef __attribute__((ext_vector_type(4))) float  f32x4;

__device__ __forceinline__ unsigned short f32_to_bf16_rne(float f) {
    uint32_t u = __builtin_bit_cast(uint32_t, f);
    u += 0x7FFFu + ((u >> 16) & 1u);
    return (unsigned short)(u >> 16);
}
__device__ __forceinline__ ushort4 cvt_f4_bf4(float4 v) {
    ushort4 h;
    h.x = f32_to_bf16_rne(v.x); h.y = f32_to_bf16_rne(v.y);
    h.z = f32_to_bf16_rne(v.z); h.w = f32_to_bf16_rne(v.w);
    return h;
}

// Repack L (fp32 row-major [K=512][N=512]) into bf16 fragment order:
// flat ushort idx = ((ks*32 + ntg)*64 + lane)*8 + e  holds L[k][n],
//   n = ntg*16 + (lane&15),  k = ks*32 + (lane>>4)*8 + e.
__global__ void prep_lt(const float* __restrict__ L, unsigned short* __restrict__ Ltf) {
    int o = blockIdx.x * 256 + threadIdx.x;
    #pragma unroll
    for (int i = 0; i < 4; ++i) {
        int idx  = o + i * 65536;
        int e    = idx & 7;
        int l    = (idx >> 3) & 63;
        int tile = idx >> 9;
        int ntg  = tile & 31;
        int ks   = tile >> 5;
        int n    = ntg * 16 + (l & 15);
        int k    = ks * 32 + (l >> 4) * 8 + e;
        Ltf[idx] = f32_to_bf16_rne(L[k * 512 + n]);
    }
}

__global__ __launch_bounds__(THREADS, 2)
void psd_main(const float* __restrict__ x, const unsigned short* __restrict__ Ltf,
              const float* __restrict__ b, const float* __restrict__ c,
              float* __restrict__ out) {
    __shared__ __align__(16) unsigned short As[2][BM * 128];  // 2 x 32 KiB K-quarter slots
    __shared__ float wpart[8][BM];
    __shared__ float bpart[BM];

    const int t    = threadIdx.x;
    const int w    = t >> 6;          // wave 0..7, owns n-cols [w*64, w*64+64)
    const int lane = t & 63;
    const int g    = lane >> 4;
    const int ln   = lane & 15;
    const int swz  = (ln & 7) << 4;
    const int tb5  = t >> 5;          // 0..15
    const int c4   = t & 31;          // float4-column within a quarter

    char* AsB = (char*)As;
    const float4* xb4 = (const float4*)x + (size_t)blockIdx.x * ROWS_PER_BLOCK * (D_DIM / 4);
    const float4* b4  = (const float4*)b;
    const float   c0  = c[0];
    const unsigned short* LtW = Ltf + (size_t)w * 2048 + (size_t)lane * 8;

    f32x4 acc[8][4];
    #pragma unroll
    for (int m = 0; m < 8; ++m)
        #pragma unroll
        for (int nt = 0; nt < 4; ++nt)
            acc[m][nt] = (f32x4){0.f, 0.f, 0.f, 0.f};
    float bacc[8] = {0.f, 0.f, 0.f, 0.f, 0.f, 0.f, 0.f, 0.f};

    // persistent B double-buffer (L2-resident fragment-order L)
    bf16x8 bcur[4];
    #pragma unroll
    for (int nt = 0; nt < 4; ++nt)
        bcur[nt] = *(const bf16x8*)(LtW + nt * 512);

    // ---- prologue: stage quarter 0 (tile 0, ql 0) into slot 0 ----
    {
        float4 bb = b4[c4];
        float4 v[8];
        #pragma unroll
        for (int j = 0; j < 8; ++j)
            v[j] = xb4[(size_t)(j * 16 + tb5) * 128 + c4];
        #pragma unroll
        for (int j = 0; j < 8; ++j) {
            bacc[j] += v[j].x * bb.x + v[j].y * bb.y + v[j].z * bb.z + v[j].w * bb.w;
            int row = j * 16 + tb5;
            *(ushort4*)(AsB + row * 256 + ((c4 * 8) ^ ((row & 7) << 4))) = cvt_f4_bf4(v[j]);
        }
    }
    __syncthreads();

#define COMPUTE_KS(KL)                                                                  \
    {                                                                                   \
        const int ksg = ql * 4 + (KL);                                                  \
        const int ksn = (ksg + 1) & 15;                                                 \
        bf16x8 bnxt[4];                                                                 \
        _Pragma("unroll")                                                               \
        for (int nt = 0; nt < 4; ++nt)                                                  \
            bnxt[nt] = *(const bf16x8*)(LtW + ksn * 16384 + nt * 512);                  \
        const int colb = (((KL) * 64 + g * 16) ^ swz);                                  \
        bf16x8 a0[4];                                                                   \
        _Pragma("unroll")                                                               \
        for (int m = 0; m < 4; ++m)                                                     \
            a0[m] = *(const bf16x8*)(rbase + (m * 16 + ln) * 256 + colb);               \
        _Pragma("unroll")                                                               \
        for (int nt = 0; nt < 4; ++nt)                                                  \
            _Pragma("unroll")                                                           \
            for (int m = 0; m < 4; ++m)                                                 \
                acc[m][nt] = __builtin_amdgcn_mfma_f32_16x16x32_bf16(a0[m], bcur[nt], acc[m][nt], 0, 0, 0); \
        bf16x8 a1[4];                                                                   \
        _Pragma("unroll")                                                               \
        for (int m = 0; m < 4; ++m)                                                     \
            a1[m] = *(const bf16x8*)(rbase + ((m + 4) * 16 + ln) * 256 + colb);         \
        _Pragma("unroll")                                                               \
        for (int nt = 0; nt < 4; ++nt)                                                  \
            _Pragma("unroll")                                                           \
            for (int m = 0; m < 4; ++m)                                                 \
                acc[m + 4][nt] = __builtin_amdgcn_mfma_f32_16x16x32_bf16(a1[m], bcur[nt], acc[m + 4][nt], 0, 0, 0); \
        _Pragma("unroll")                                                               \
        for (int nt = 0; nt < 4; ++nt) bcur[nt] = bnxt[nt];                             \
    }

#define WRITE_BATCH(VV, J0)                                                             \
    {                                                                                   \
        _Pragma("unroll")                                                               \
        for (int jj = 0; jj < 4; ++jj) {                                                \
            const int j = (J0) + jj;                                                    \
            bacc[j] += (VV)[jj].x * bb.x + (VV)[jj].y * bb.y                            \
                     + (VV)[jj].z * bb.z + (VV)[jj].w * bb.w;                           \
            const int row = j * 16 + tb5;                                               \
            *(ushort4*)(wbase + row * 256 + ((c4 * 8) ^ ((row & 7) << 4))) = cvt_f4_bf4((VV)[jj]); \
        }                                                                               \
    }

    #pragma unroll 1
    for (int qp = 0; qp < 8; ++qp) {
        #pragma unroll
        for (int qh = 0; qh < 2; ++qh) {
            const int q   = qp * 2 + qh;
            const int ql  = q & 3;
            const int tt  = q >> 2;
            const bool has_next = (q + 1 < NSTEPS);
            const int qnl = (q + 1) & 3;
            const int qnt = (q + 1) >> 2;
            char* rbase = AsB + qh * 32768;          // compute slot (static)
            char* wbase = AsB + (qh ^ 1) * 32768;    // stage slot (static)

            // issue first half of next quarter's loads (fly under ks0-1)
            float4 bb = {0.f, 0.f, 0.f, 0.f};
            float4 va[4];
            if (has_next) {
                bb = b4[qnl * 32 + c4];
                #pragma unroll
                for (int j = 0; j < 4; ++j)
                    va[j] = xb4[(size_t)(qnt * 128 + j * 16 + tb5) * 128 + qnl * 32 + c4];
            }

            COMPUTE_KS(0)
            COMPUTE_KS(1)

            if (has_next) WRITE_BATCH(va, 0)

            float4 vb[4];
            if (has_next) {
                #pragma unroll
                for (int j = 0; j < 4; ++j)
                    vb[j] = xb4[(size_t)(qnt * 128 + (j + 4) * 16 + tb5) * 128 + qnl * 32 + c4];
            }

            COMPUTE_KS(2)
            COMPUTE_KS(3)

            if (has_next) WRITE_BATCH(vb, 4)

            // staged quarter completed a tile -> reduce x.b partials
            if (has_next && qnl == 3) {
                #pragma unroll
                for (int j = 0; j < 8; ++j) {
                    float s = bacc[j];
                    s += __shfl_xor(s, 1);  s += __shfl_xor(s, 2);
                    s += __shfl_xor(s, 4);  s += __shfl_xor(s, 8);
                    s += __shfl_xor(s, 16);
                    if ((lane & 31) == 0) bpart[j * 16 + tb5] = s;
                    bacc[j] = 0.f;
                }
            }
            // computed quarter completed a tile -> quad rowsum reduce
            if (ql == 3) {
                #pragma unroll
                for (int m = 0; m < 8; ++m)
                    #pragma unroll
                    for (int r = 0; r < 4; ++r) {
                        float s = 0.f;
                        #pragma unroll
                        for (int nt = 0; nt < 4; ++nt) { float vv = acc[m][nt][r]; s += vv * vv; }
                        s += __shfl_xor(s, 1);  s += __shfl_xor(s, 2);
                        s += __shfl_xor(s, 4);  s += __shfl_xor(s, 8);
                        if (ln == 0) wpart[w][m * 16 + g * 4 + r] = s;
                    }
                #pragma unroll
                for (int m = 0; m < 8; ++m)
                    #pragma unroll
                    for (int nt = 0; nt < 4; ++nt)
                        acc[m][nt] = (f32x4){0.f, 0.f, 0.f, 0.f};
            }
            __syncthreads();
            if (ql == 3 && t < BM) {
                float y = c0 + bpart[t];
                #pragma unroll
                for (int ww = 0; ww < 8; ++ww) y += wpart[ww][t];
                out[(size_t)blockIdx.x * ROWS_PER_BLOCK + tt * BM + t] = y;
            }
        }
    }
#undef COMPUTE_KS
#undef WRITE_BATCH
}

extern "C" void kernel_launch(void* const* d_in, const int* in_sizes, int n_in,
                              void* d_out, int out_size, void* d_ws, size_t ws_size,
                              hipStream_t stream) {
    const float* x = (const float*)d_in[0];
    const float* L = (const float*)d_in[1];
    const float* b = (const float*)d_in[2];
    const float* c = (const float*)d_in[3];
    float* out = (float*)d_out;
    unsigned short* Ltf = (unsigned short*)d_ws;   // 512 KiB

    prep_lt<<<256, 256, 0, stream>>>(L, Ltf);
    psd_main<<<NBLOCKS, THREADS, 0, stream>>>(x, Ltf, b, c, out);
}